// Round 1
// baseline (230.383 us; speedup 1.0000x reference)
//
#include <hip/hip_runtime.h>

typedef __attribute__((ext_vector_type(8))) short short8;
typedef __attribute__((ext_vector_type(4))) float f32x4;

#define NEGBIG -1e10f

__device__ __forceinline__ unsigned short f2bf(float x) {
  unsigned int u = __float_as_uint(x);
  u += 0x7FFFu + ((u >> 16) & 1u);          // round-to-nearest-even
  return (unsigned short)(u >> 16);
}
__device__ __forceinline__ float bf2f(unsigned short h) {
  return __uint_as_float(((unsigned int)h) << 16);
}

// ---------------- pooling kernel ----------------
// One block per (side, b, f). 512 threads = 8 waves.
// Stages the 64x768 token panel in LDS (bf16, 96KB) so HBM is read ONCE.
__global__ __launch_bounds__(512) void pool_kernel(
    const float* __restrict__ left, const float* __restrict__ right,
    const float* __restrict__ femb_l, const float* __restrict__ femb_r,
    const float* __restrict__ empty_attr,
    unsigned short* __restrict__ concat)   // [B, 8, 768] bf16
{
  const int D = 768;
  int bid  = blockIdx.x;      // 0..2047
  int side = bid >> 10;       // 0 = left, 1 = right
  int rem  = bid & 1023;      // b*4 + f
  int f    = rem & 3;
  int b    = rem >> 2;
  const float* v    = (side ? right : left) + (size_t)rem * 64 * D;
  const float* femb = (side ? femb_r : femb_l) + f * D;

  int tid  = threadIdx.x;
  int wave = tid >> 6;
  int lane = tid & 63;

  __shared__ unsigned short v_lds[64 * 768];  // 96 KB
  __shared__ float logits_lds[64];
  __shared__ int   mask_lds[64];
  __shared__ float w_lds[64];
  __shared__ int   attr_flag;

  // preload femb row into registers (12 per lane, reused for 8 tokens)
  float fr[12];
  #pragma unroll
  for (int j = 0; j < 12; ++j) fr[j] = femb[lane + 64 * j];

  // Phase A: each wave handles 8 tokens; dot(v_token, femb), nonzero mask,
  // and stage v into LDS as bf16.
  #pragma unroll
  for (int t = 0; t < 8; ++t) {
    int l = wave * 8 + t;
    const float* vp = v + l * D;
    float xs[12];
    #pragma unroll
    for (int j = 0; j < 12; ++j) xs[j] = vp[lane + 64 * j];
    float dot = 0.f;
    int nz = 0;
    #pragma unroll
    for (int j = 0; j < 12; ++j) {
      dot += xs[j] * fr[j];
      nz |= (xs[j] != 0.f);
      v_lds[l * 768 + lane + 64 * j] = f2bf(xs[j]);
    }
    #pragma unroll
    for (int s = 32; s > 0; s >>= 1) dot += __shfl_xor(dot, s);
    int any_nz = __any(nz);
    if (lane == 0) {
      logits_lds[l] = dot + (any_nz ? 0.f : NEGBIG);
      mask_lds[l]   = any_nz;
    }
  }
  __syncthreads();

  // Phase B: masked softmax over 64 tokens, done by wave 0 (one token/lane)
  if (wave == 0) {
    float lg = logits_lds[lane];
    float m = lg;
    #pragma unroll
    for (int s = 32; s > 0; s >>= 1) m = fmaxf(m, __shfl_xor(m, s));
    float e = __expf(lg - m);
    float ssum = e;
    #pragma unroll
    for (int s = 32; s > 0; s >>= 1) ssum += __shfl_xor(ssum, s);
    w_lds[lane] = e / ssum;
    int am = __any(mask_lds[lane] != 0);
    if (lane == 0) attr_flag = am;
  }
  __syncthreads();

  // Phase C: summary[d] = sum_l w[l] * v[l][d]  (read from LDS)
  size_t base = ((size_t)b * 8 + side * 4 + f) * 768;
  int has = attr_flag;
  #pragma unroll
  for (int rep = 0; rep < 2; ++rep) {
    int d = tid + rep * 512;
    if (d < 768) {
      float acc = 0.f;
      #pragma unroll 8
      for (int l = 0; l < 64; ++l) acc += w_lds[l] * bf2f(v_lds[l * 768 + d]);
      float o = has ? acc : empty_attr[d];
      concat[base + d] = f2bf(o);
    }
  }
}

// ---------------- W1 f32 -> bf16 conversion ----------------
__global__ __launch_bounds__(256) void convert_w1(
    const float* __restrict__ src, unsigned short* __restrict__ dst, int n4)
{
  int i = blockIdx.x * blockDim.x + threadIdx.x;
  if (i < n4) {
    float4 vv = ((const float4*)src)[i];
    ushort4 o;
    o.x = f2bf(vv.x); o.y = f2bf(vv.y); o.z = f2bf(vv.z); o.w = f2bf(vv.w);
    ((ushort4*)dst)[i] = o;
  }
}

// ---------------- GEMM1: H = relu(A @ W1^T + b1) ----------------
// A [256,6144] bf16 (K-contiguous), W1b [1600,6144] bf16 (K-contiguous).
// Block = 4 waves (2x2), each wave computes a 32x32 tile via 16x16x32 MFMA.
__global__ __launch_bounds__(256) void gemm1_kernel(
    const unsigned short* __restrict__ A,
    const unsigned short* __restrict__ Wb,
    const float* __restrict__ bias1,
    float* __restrict__ H)
{
  const int K = 6144, N = 1600;
  int tid = threadIdx.x;
  int wave = tid >> 6, lane = tid & 63;
  int wm = wave >> 1, wn = wave & 1;
  int row0 = blockIdx.x * 64 + wm * 32;
  int col0 = blockIdx.y * 64 + wn * 32;

  int lr = lane & 15;
  int lk = (lane >> 4) * 8;

  const short* a0 = (const short*)A  + (size_t)(row0 + lr) * K + lk;
  const short* a1 = a0 + 16 * K;
  const short* b0 = (const short*)Wb + (size_t)(col0 + lr) * K + lk;
  const short* b1 = b0 + 16 * K;

  f32x4 acc00 = {}, acc01 = {}, acc10 = {}, acc11 = {};

  #pragma unroll 4
  for (int k = 0; k < K; k += 32) {
    short8 af0 = *(const short8*)(a0 + k);
    short8 af1 = *(const short8*)(a1 + k);
    short8 bf0 = *(const short8*)(b0 + k);
    short8 bf1 = *(const short8*)(b1 + k);
    acc00 = __builtin_amdgcn_mfma_f32_16x16x32_bf16(af0, bf0, acc00, 0, 0, 0);
    acc01 = __builtin_amdgcn_mfma_f32_16x16x32_bf16(af0, bf1, acc01, 0, 0, 0);
    acc10 = __builtin_amdgcn_mfma_f32_16x16x32_bf16(af1, bf0, acc10, 0, 0, 0);
    acc11 = __builtin_amdgcn_mfma_f32_16x16x32_bf16(af1, bf1, acc11, 0, 0, 0);
  }

  // C/D layout: col = lane&15, row = (lane>>4)*4 + reg
  int ccol = lane & 15;
  int crow = (lane >> 4) * 4;
  f32x4 accs[2][2] = {{acc00, acc01}, {acc10, acc11}};
  #pragma unroll
  for (int i = 0; i < 2; ++i) {
    #pragma unroll
    for (int j = 0; j < 2; ++j) {
      int r = row0 + i * 16 + crow;
      int c = col0 + j * 16 + ccol;
      float bs = bias1[c];
      #pragma unroll
      for (int q = 0; q < 4; ++q) {
        float vout = accs[i][j][q] + bs;
        H[(size_t)(r + q) * N + c] = fmaxf(vout, 0.f);
      }
    }
  }
}

// ---------------- GEMM2: out = H @ W2^T + b2 ----------------
__global__ __launch_bounds__(64) void gemm2_kernel(
    const float* __restrict__ H, const float* __restrict__ W2,
    const float* __restrict__ b2, float* __restrict__ out)
{
  int b = blockIdx.x, lane = threadIdx.x;
  float s0 = 0.f, s1 = 0.f;
  for (int k = lane; k < 1600; k += 64) {
    float h = H[b * 1600 + k];
    s0 += h * W2[k];
    s1 += h * W2[1600 + k];
  }
  #pragma unroll
  for (int s = 32; s > 0; s >>= 1) {
    s0 += __shfl_xor(s0, s);
    s1 += __shfl_xor(s1, s);
  }
  if (lane == 0) {
    out[b * 2 + 0] = s0 + b2[0];
    out[b * 2 + 1] = s1 + b2[1];
  }
}

extern "C" void kernel_launch(void* const* d_in, const int* in_sizes, int n_in,
                              void* d_out, int out_size, void* d_ws, size_t ws_size,
                              hipStream_t stream) {
  const float* left       = (const float*)d_in[0];
  const float* right      = (const float*)d_in[1];
  const float* femb_l     = (const float*)d_in[2];
  const float* femb_r     = (const float*)d_in[3];
  const float* empty_attr = (const float*)d_in[4];
  const float* W1         = (const float*)d_in[5];
  const float* b1         = (const float*)d_in[6];
  const float* W2         = (const float*)d_in[7];
  const float* b2         = (const float*)d_in[8];
  float* out = (float*)d_out;

  char* ws = (char*)d_ws;
  unsigned short* concat = (unsigned short*)ws;                    // 256*6144*2  = 3,145,728 B
  unsigned short* W1b    = (unsigned short*)(ws + 3145728);        // 1600*6144*2 = 19,660,800 B
  float*          H      = (float*)(ws + 3145728 + 19660800);      // 256*1600*4  = 1,638,400 B

  hipLaunchKernelGGL(pool_kernel, dim3(2048), dim3(512), 0, stream,
                     left, right, femb_l, femb_r, empty_attr, concat);
  hipLaunchKernelGGL(convert_w1, dim3(9600), dim3(256), 0, stream,
                     W1, W1b, 2457600);
  hipLaunchKernelGGL(gemm1_kernel, dim3(4, 25), dim3(256), 0, stream,
                     concat, W1b, b1, H);
  hipLaunchKernelGGL(gemm2_kernel, dim3(256), dim3(64), 0, stream,
                     H, W2, b2, out);
}

// Round 2
// 218.853 us; speedup vs baseline: 1.0527x; 1.0527x over previous
//
#include <hip/hip_runtime.h>

typedef __attribute__((ext_vector_type(8))) short short8;
typedef __attribute__((ext_vector_type(4))) float f32x4;

#define NEGBIG -1e10f

__device__ __forceinline__ unsigned short f2bf(float x) {
  unsigned int u = __float_as_uint(x);
  u += 0x7FFFu + ((u >> 16) & 1u);          // round-to-nearest-even
  return (unsigned short)(u >> 16);
}

__device__ __forceinline__ float4 mul4(float4 a, float s) {
  float4 r; r.x = a.x*s; r.y = a.y*s; r.z = a.z*s; r.w = a.w*s; return r;
}
__device__ __forceinline__ float4 add4(float4 a, float4 b) {
  float4 r; r.x = a.x+b.x; r.y = a.y+b.y; r.z = a.z+b.z; r.w = a.w+b.w; return r;
}
// a = a*sc + e*x
__device__ __forceinline__ float4 upd4(float4 a, float sc, float e, float4 x) {
  float4 r;
  r.x = a.x*sc + e*x.x; r.y = a.y*sc + e*x.y;
  r.z = a.z*sc + e*x.z; r.w = a.w*sc + e*x.w;
  return r;
}

// ---------------- pooling kernel (online softmax, register-resident) --------
// One block (4 waves, 256 thr) per (side, b, f). Each wave owns 16 tokens and
// keeps a running (m, s, acc[12]) flash-style state; 4-way merge via 12KB LDS.
// Every input byte is read from HBM exactly once; no panel staging.
__global__ __launch_bounds__(256, 6) void pool_kernel(
    const float* __restrict__ left, const float* __restrict__ right,
    const float* __restrict__ femb_l, const float* __restrict__ femb_r,
    const float* __restrict__ empty_attr,
    unsigned short* __restrict__ concat)   // [B, 8, 768] bf16
{
  int bid  = blockIdx.x;      // 0..2047
  int side = bid >> 10;       // 0 = left, 1 = right
  int rem  = bid & 1023;      // b*4 + f
  int f    = rem & 3;
  int b    = rem >> 2;
  const float* v    = (side ? right : left) + (size_t)rem * 64 * 768;
  const float* femb = (side ? femb_r : femb_l) + f * 768;

  int tid = threadIdx.x, wave = tid >> 6, lane = tid & 63;

  // femb fragment: lane holds d = j*256 + lane*4 + c
  const float4* fp = (const float4*)femb;
  float4 f0 = fp[lane], f1 = fp[lane + 64], f2 = fp[lane + 128];

  float4 a0 = {0,0,0,0}, a1 = {0,0,0,0}, a2 = {0,0,0,0};
  float m = -3.0e38f, s = 0.f;
  int wnz = 0;

  const float4* vp = (const float4*)(v + (size_t)wave * 16 * 768);
  #pragma unroll 2
  for (int t = 0; t < 16; ++t) {
    float4 x0 = vp[t * 192 + lane];
    float4 x1 = vp[t * 192 + 64 + lane];
    float4 x2 = vp[t * 192 + 128 + lane];

    float dot = x0.x*f0.x + x0.y*f0.y + x0.z*f0.z + x0.w*f0.w
              + x1.x*f1.x + x1.y*f1.y + x1.z*f1.z + x1.w*f1.w
              + x2.x*f2.x + x2.y*f2.y + x2.z*f2.z + x2.w*f2.w;
    int nz = (x0.x!=0.f) | (x0.y!=0.f) | (x0.z!=0.f) | (x0.w!=0.f)
           | (x1.x!=0.f) | (x1.y!=0.f) | (x1.z!=0.f) | (x1.w!=0.f)
           | (x2.x!=0.f) | (x2.y!=0.f) | (x2.z!=0.f) | (x2.w!=0.f);
    #pragma unroll
    for (int sh = 32; sh > 0; sh >>= 1) dot += __shfl_xor(dot, sh);
    int any_nz = __any(nz);
    wnz |= any_nz;
    float logit = any_nz ? dot : dot + NEGBIG;

    float mn = fmaxf(m, logit);
    float e  = __expf(logit - mn);
    float sc = __expf(m - mn);   // 0 on first token (m=-3e38), 1 when no new max
    s  = s * sc + e;
    a0 = upd4(a0, sc, e, x0);
    a1 = upd4(a1, sc, e, x1);
    a2 = upd4(a2, sc, e, x2);
    m  = mn;
  }

  // ---- cross-wave merge ----
  __shared__ float m_lds[4], s_lds[4];
  __shared__ int   nz_lds[4];
  __shared__ float acc_lds[4 * 768];   // 12 KB

  if (lane == 0) { m_lds[wave] = m; nz_lds[wave] = wnz; }
  __syncthreads();
  float M = fmaxf(fmaxf(m_lds[0], m_lds[1]), fmaxf(m_lds[2], m_lds[3]));
  float scale = __expf(m - M);
  if (lane == 0) s_lds[wave] = s * scale;
  float4* al = (float4*)acc_lds;
  al[wave * 192 +       lane] = mul4(a0, scale);
  al[wave * 192 +  64 + lane] = mul4(a1, scale);
  al[wave * 192 + 128 + lane] = mul4(a2, scale);
  __syncthreads();

  if (tid < 192) {   // d = tid*4 .. tid*4+3
    float4 A = add4(add4(al[tid], al[192 + tid]),
                    add4(al[384 + tid], al[576 + tid]));
    float S = s_lds[0] + s_lds[1] + s_lds[2] + s_lds[3];
    int has = nz_lds[0] | nz_lds[1] | nz_lds[2] | nz_lds[3];
    float4 r;
    if (has) { float inv = 1.f / S; r = mul4(A, inv); }
    else     { r = ((const float4*)empty_attr)[tid]; }
    ushort4 o;
    o.x = f2bf(r.x); o.y = f2bf(r.y); o.z = f2bf(r.z); o.w = f2bf(r.w);
    size_t base = ((size_t)b * 8 + side * 4 + f) * 192;  // ushort4 units
    ((ushort4*)concat)[base + tid] = o;
  }
}

// ---------------- GEMM1: H = relu(A @ W1^T + b1), W1 converted inline ------
// A [256,6144] bf16 (K-contiguous), W1 [1600,6144] f32 (K-contiguous).
// Block = 4 waves (2x2), each wave computes a 32x32 tile via 16x16x32 MFMA.
__global__ __launch_bounds__(256) void gemm1_kernel(
    const unsigned short* __restrict__ A,
    const float* __restrict__ W1,
    const float* __restrict__ bias1,
    float* __restrict__ H)
{
  const int K = 6144, N = 1600;
  int tid = threadIdx.x;
  int wave = tid >> 6, lane = tid & 63;
  int wm = wave >> 1, wn = wave & 1;
  int row0 = blockIdx.x * 64 + wm * 32;
  int col0 = blockIdx.y * 64 + wn * 32;

  int lr = lane & 15;
  int lk = (lane >> 4) * 8;

  const short* a0 = (const short*)A + (size_t)(row0 + lr) * K + lk;
  const short* a1 = a0 + 16 * K;
  const float* w0 = W1 + (size_t)(col0 + lr) * K + lk;
  const float* w1 = w0 + 16 * K;

  f32x4 acc00 = {}, acc01 = {}, acc10 = {}, acc11 = {};

  #pragma unroll 2
  for (int k = 0; k < K; k += 32) {
    short8 af0 = *(const short8*)(a0 + k);
    short8 af1 = *(const short8*)(a1 + k);
    float4 w0a = *(const float4*)(w0 + k);
    float4 w0b = *(const float4*)(w0 + k + 4);
    float4 w1a = *(const float4*)(w1 + k);
    float4 w1b = *(const float4*)(w1 + k + 4);
    short8 bf0, bf1;
    bf0[0] = (short)f2bf(w0a.x); bf0[1] = (short)f2bf(w0a.y);
    bf0[2] = (short)f2bf(w0a.z); bf0[3] = (short)f2bf(w0a.w);
    bf0[4] = (short)f2bf(w0b.x); bf0[5] = (short)f2bf(w0b.y);
    bf0[6] = (short)f2bf(w0b.z); bf0[7] = (short)f2bf(w0b.w);
    bf1[0] = (short)f2bf(w1a.x); bf1[1] = (short)f2bf(w1a.y);
    bf1[2] = (short)f2bf(w1a.z); bf1[3] = (short)f2bf(w1a.w);
    bf1[4] = (short)f2bf(w1b.x); bf1[5] = (short)f2bf(w1b.y);
    bf1[6] = (short)f2bf(w1b.z); bf1[7] = (short)f2bf(w1b.w);
    acc00 = __builtin_amdgcn_mfma_f32_16x16x32_bf16(af0, bf0, acc00, 0, 0, 0);
    acc01 = __builtin_amdgcn_mfma_f32_16x16x32_bf16(af0, bf1, acc01, 0, 0, 0);
    acc10 = __builtin_amdgcn_mfma_f32_16x16x32_bf16(af1, bf0, acc10, 0, 0, 0);
    acc11 = __builtin_amdgcn_mfma_f32_16x16x32_bf16(af1, bf1, acc11, 0, 0, 0);
  }

  // C/D layout: col = lane&15, row = (lane>>4)*4 + reg
  int ccol = lane & 15;
  int crow = (lane >> 4) * 4;
  f32x4 accs[2][2] = {{acc00, acc01}, {acc10, acc11}};
  #pragma unroll
  for (int i = 0; i < 2; ++i) {
    #pragma unroll
    for (int j = 0; j < 2; ++j) {
      int r = row0 + i * 16 + crow;
      int c = col0 + j * 16 + ccol;
      float bs = bias1[c];
      #pragma unroll
      for (int q = 0; q < 4; ++q) {
        float vout = accs[i][j][q] + bs;
        H[(size_t)(r + q) * N + c] = fmaxf(vout, 0.f);
      }
    }
  }
}

// ---------------- GEMM2: out = H @ W2^T + b2 ----------------
__global__ __launch_bounds__(64) void gemm2_kernel(
    const float* __restrict__ H, const float* __restrict__ W2,
    const float* __restrict__ b2, float* __restrict__ out)
{
  int b = blockIdx.x, lane = threadIdx.x;
  float s0 = 0.f, s1 = 0.f;
  for (int k = lane; k < 1600; k += 64) {
    float h = H[b * 1600 + k];
    s0 += h * W2[k];
    s1 += h * W2[1600 + k];
  }
  #pragma unroll
  for (int s = 32; s > 0; s >>= 1) {
    s0 += __shfl_xor(s0, s);
    s1 += __shfl_xor(s1, s);
  }
  if (lane == 0) {
    out[b * 2 + 0] = s0 + b2[0];
    out[b * 2 + 1] = s1 + b2[1];
  }
}

extern "C" void kernel_launch(void* const* d_in, const int* in_sizes, int n_in,
                              void* d_out, int out_size, void* d_ws, size_t ws_size,
                              hipStream_t stream) {
  const float* left       = (const float*)d_in[0];
  const float* right      = (const float*)d_in[1];
  const float* femb_l     = (const float*)d_in[2];
  const float* femb_r     = (const float*)d_in[3];
  const float* empty_attr = (const float*)d_in[4];
  const float* W1         = (const float*)d_in[5];
  const float* b1         = (const float*)d_in[6];
  const float* W2         = (const float*)d_in[7];
  const float* b2         = (const float*)d_in[8];
  float* out = (float*)d_out;

  char* ws = (char*)d_ws;
  unsigned short* concat = (unsigned short*)ws;               // 256*6144*2 = 3,145,728 B
  float*          H      = (float*)(ws + 3145728);            // 256*1600*4 = 1,638,400 B

  hipLaunchKernelGGL(pool_kernel, dim3(2048), dim3(256), 0, stream,
                     left, right, femb_l, femb_r, empty_attr, concat);
  hipLaunchKernelGGL(gemm1_kernel, dim3(4, 25), dim3(256), 0, stream,
                     concat, W1, b1, H);
  hipLaunchKernelGGL(gemm2_kernel, dim3(256), dim3(64), 0, stream,
                     H, W2, b2, out);
}

// Round 3
// 137.150 us; speedup vs baseline: 1.6798x; 1.5957x over previous
//
#include <hip/hip_runtime.h>

typedef __attribute__((ext_vector_type(8))) short short8;
typedef __attribute__((ext_vector_type(4))) short short4_t;
typedef __attribute__((ext_vector_type(4))) float f32x4;

#define NEGBIG -1e10f

__device__ __forceinline__ unsigned short f2bf(float x) {
  unsigned int u = __float_as_uint(x);
  u += 0x7FFFu + ((u >> 16) & 1u);          // round-to-nearest-even
  return (unsigned short)(u >> 16);
}

__device__ __forceinline__ float4 mul4(float4 a, float s) {
  float4 r; r.x = a.x*s; r.y = a.y*s; r.z = a.z*s; r.w = a.w*s; return r;
}
__device__ __forceinline__ float4 add4(float4 a, float4 b) {
  float4 r; r.x = a.x+b.x; r.y = a.y+b.y; r.z = a.z+b.z; r.w = a.w+b.w; return r;
}
// a = a*sc + e*x
__device__ __forceinline__ float4 upd4(float4 a, float sc, float e, float4 x) {
  float4 r;
  r.x = a.x*sc + e*x.x; r.y = a.y*sc + e*x.y;
  r.z = a.z*sc + e*x.z; r.w = a.w*sc + e*x.w;
  return r;
}

// ---------------- pooling kernel (online softmax, register-resident) --------
// One block (4 waves, 256 thr) per (side, b, f). Each wave owns 16 tokens and
// keeps a running (m, s, acc[12]) flash-style state; 4-way merge via 12KB LDS.
__global__ __launch_bounds__(256, 6) void pool_kernel(
    const float* __restrict__ left, const float* __restrict__ right,
    const float* __restrict__ femb_l, const float* __restrict__ femb_r,
    const float* __restrict__ empty_attr,
    unsigned short* __restrict__ concat)   // [B, 8, 768] bf16
{
  int bid  = blockIdx.x;      // 0..2047
  int side = bid >> 10;       // 0 = left, 1 = right
  int rem  = bid & 1023;      // b*4 + f
  int f    = rem & 3;
  int b    = rem >> 2;
  const float* v    = (side ? right : left) + (size_t)rem * 64 * 768;
  const float* femb = (side ? femb_r : femb_l) + f * 768;

  int tid = threadIdx.x, wave = tid >> 6, lane = tid & 63;

  const float4* fp = (const float4*)femb;
  float4 f0 = fp[lane], f1 = fp[lane + 64], f2 = fp[lane + 128];

  float4 a0 = {0,0,0,0}, a1 = {0,0,0,0}, a2 = {0,0,0,0};
  float m = -3.0e38f, s = 0.f;
  int wnz = 0;

  const float4* vp = (const float4*)(v + (size_t)wave * 16 * 768);
  #pragma unroll 2
  for (int t = 0; t < 16; ++t) {
    float4 x0 = vp[t * 192 + lane];
    float4 x1 = vp[t * 192 + 64 + lane];
    float4 x2 = vp[t * 192 + 128 + lane];

    float dot = x0.x*f0.x + x0.y*f0.y + x0.z*f0.z + x0.w*f0.w
              + x1.x*f1.x + x1.y*f1.y + x1.z*f1.z + x1.w*f1.w
              + x2.x*f2.x + x2.y*f2.y + x2.z*f2.z + x2.w*f2.w;
    int nz = (x0.x!=0.f) | (x0.y!=0.f) | (x0.z!=0.f) | (x0.w!=0.f)
           | (x1.x!=0.f) | (x1.y!=0.f) | (x1.z!=0.f) | (x1.w!=0.f)
           | (x2.x!=0.f) | (x2.y!=0.f) | (x2.z!=0.f) | (x2.w!=0.f);
    #pragma unroll
    for (int sh = 32; sh > 0; sh >>= 1) dot += __shfl_xor(dot, sh);
    int any_nz = __any(nz);
    wnz |= any_nz;
    float logit = any_nz ? dot : dot + NEGBIG;

    float mn = fmaxf(m, logit);
    float e  = __expf(logit - mn);
    float sc = __expf(m - mn);
    s  = s * sc + e;
    a0 = upd4(a0, sc, e, x0);
    a1 = upd4(a1, sc, e, x1);
    a2 = upd4(a2, sc, e, x2);
    m  = mn;
  }

  __shared__ float m_lds[4], s_lds[4];
  __shared__ int   nz_lds[4];
  __shared__ float acc_lds[4 * 768];   // 12 KB

  if (lane == 0) { m_lds[wave] = m; nz_lds[wave] = wnz; }
  __syncthreads();
  float M = fmaxf(fmaxf(m_lds[0], m_lds[1]), fmaxf(m_lds[2], m_lds[3]));
  float scale = __expf(m - M);
  if (lane == 0) s_lds[wave] = s * scale;
  float4* al = (float4*)acc_lds;
  al[wave * 192 +       lane] = mul4(a0, scale);
  al[wave * 192 +  64 + lane] = mul4(a1, scale);
  al[wave * 192 + 128 + lane] = mul4(a2, scale);
  __syncthreads();

  if (tid < 192) {
    float4 A = add4(add4(al[tid], al[192 + tid]),
                    add4(al[384 + tid], al[576 + tid]));
    float S = s_lds[0] + s_lds[1] + s_lds[2] + s_lds[3];
    int has = nz_lds[0] | nz_lds[1] | nz_lds[2] | nz_lds[3];
    float4 r;
    if (has) { float inv = 1.f / S; r = mul4(A, inv); }
    else     { r = ((const float4*)empty_attr)[tid]; }
    ushort4 o;
    o.x = f2bf(r.x); o.y = f2bf(r.y); o.z = f2bf(r.z); o.w = f2bf(r.w);
    size_t base = ((size_t)b * 8 + side * 4 + f) * 192;
    ((ushort4*)concat)[base + tid] = o;
  }
}

// ---------------- GEMM1 split-K ----------------
// A [256,6144] bf16 (K-contig). W1 [1600,6144] f32 (K-contig).
// Grid (100 col-tiles, 8 K-chunks). Block = 4 waves. Each block stages its
// EXCLUSIVE 16col x 768K W1 tile in LDS (bf16, 24.6KB) -> W1 read once total.
// Wave w computes rows 64w..64w+63 (4 MFMA row-tiles) x 16 cols.
// Hpart[kc][256][1600] f32 partials (every element written each launch).
__global__ __launch_bounds__(256) void gemm1_kernel(
    const unsigned short* __restrict__ A,
    const float* __restrict__ W1,
    float* __restrict__ Hpart)
{
  const int K = 6144, N = 1600, KC = 768;
  int colb = blockIdx.x;          // 0..99
  int kc   = blockIdx.y;          // 0..7
  int col0 = colb * 16;
  int tid = threadIdx.x, wave = tid >> 6, lane = tid & 63;

  // [kblk=96][col=16][k&7=8] bf16 -> ds_read_b128 with 16B lane stride
  __shared__ short wlds[96 * 16 * 8];

  const float* wsrc = W1 + (size_t)col0 * K + kc * KC;
  #pragma unroll
  for (int i = 0; i < 12; ++i) {
    int flat4 = tid + 256 * i;          // float4 idx within 16x768 tile
    int col = flat4 / 192;
    int k   = (flat4 % 192) * 4;
    float4 w = *(const float4*)(wsrc + (size_t)col * K + k);
    short4_t o;
    o[0] = (short)f2bf(w.x); o[1] = (short)f2bf(w.y);
    o[2] = (short)f2bf(w.z); o[3] = (short)f2bf(w.w);
    *(short4_t*)(wlds + (k >> 3) * 128 + col * 8 + (k & 7)) = o;
  }
  __syncthreads();

  int lr = lane & 15, lk = (lane >> 4) * 8;
  const short* a0 = (const short*)A + (size_t)(wave * 64 + lr) * K + kc * KC + lk;
  const short* bptr = wlds + (lane >> 4) * 128 + lr * 8;

  f32x4 acc0 = {}, acc1 = {}, acc2 = {}, acc3 = {};

  #pragma unroll 4
  for (int ks = 0; ks < 24; ++ks) {
    short8 bf  = *(const short8*)(bptr + ks * 512);
    short8 af0 = *(const short8*)(a0 + ks * 32);
    short8 af1 = *(const short8*)(a0 + ks * 32 + 16 * K);
    short8 af2 = *(const short8*)(a0 + ks * 32 + 32 * K);
    short8 af3 = *(const short8*)(a0 + ks * 32 + 48 * K);
    acc0 = __builtin_amdgcn_mfma_f32_16x16x32_bf16(af0, bf, acc0, 0, 0, 0);
    acc1 = __builtin_amdgcn_mfma_f32_16x16x32_bf16(af1, bf, acc1, 0, 0, 0);
    acc2 = __builtin_amdgcn_mfma_f32_16x16x32_bf16(af2, bf, acc2, 0, 0, 0);
    acc3 = __builtin_amdgcn_mfma_f32_16x16x32_bf16(af3, bf, acc3, 0, 0, 0);
  }

  // C/D: col = lane&15, row = (lane>>4)*4 + q
  int ccol = lane & 15;
  int crow = (lane >> 4) * 4;
  float* hp = Hpart + (size_t)kc * 256 * N + (size_t)col0 + ccol;
  f32x4 accs[4] = {acc0, acc1, acc2, acc3};
  #pragma unroll
  for (int i = 0; i < 4; ++i) {
    int r = wave * 64 + i * 16 + crow;
    #pragma unroll
    for (int q = 0; q < 4; ++q)
      hp[(size_t)(r + q) * N] = accs[i][q];
  }
}

// ---------------- epilogue: reduce split-K + bias + relu + head GEMM -------
__global__ __launch_bounds__(256) void epilogue_kernel(
    const float* __restrict__ Hpart, const float* __restrict__ b1,
    const float* __restrict__ W2, const float* __restrict__ b2,
    float* __restrict__ out)
{
  const int N = 1600;
  int b = blockIdx.x, tid = threadIdx.x;
  int wave = tid >> 6, lane = tid & 63;
  float s0 = 0.f, s1 = 0.f;
  for (int c = tid; c < N; c += 256) {
    float acc = 0.f;
    #pragma unroll
    for (int kc = 0; kc < 8; ++kc)
      acc += Hpart[((size_t)kc * 256 + b) * N + c];
    float h = fmaxf(acc + b1[c], 0.f);
    s0 += h * W2[c];
    s1 += h * W2[N + c];
  }
  #pragma unroll
  for (int s = 32; s > 0; s >>= 1) {
    s0 += __shfl_xor(s0, s);
    s1 += __shfl_xor(s1, s);
  }
  __shared__ float r0[4], r1[4];
  if (lane == 0) { r0[wave] = s0; r1[wave] = s1; }
  __syncthreads();
  if (tid == 0) {
    out[b * 2 + 0] = r0[0] + r0[1] + r0[2] + r0[3] + b2[0];
    out[b * 2 + 1] = r1[0] + r1[1] + r1[2] + r1[3] + b2[1];
  }
}

extern "C" void kernel_launch(void* const* d_in, const int* in_sizes, int n_in,
                              void* d_out, int out_size, void* d_ws, size_t ws_size,
                              hipStream_t stream) {
  const float* left       = (const float*)d_in[0];
  const float* right      = (const float*)d_in[1];
  const float* femb_l     = (const float*)d_in[2];
  const float* femb_r     = (const float*)d_in[3];
  const float* empty_attr = (const float*)d_in[4];
  const float* W1         = (const float*)d_in[5];
  const float* b1         = (const float*)d_in[6];
  const float* W2         = (const float*)d_in[7];
  const float* b2         = (const float*)d_in[8];
  float* out = (float*)d_out;

  char* ws = (char*)d_ws;
  unsigned short* concat = (unsigned short*)ws;               // 256*6144*2 = 3,145,728 B
  float*          Hpart  = (float*)(ws + 3145728);            // 8*256*1600*4 = 13,107,200 B

  hipLaunchKernelGGL(pool_kernel, dim3(2048), dim3(256), 0, stream,
                     left, right, femb_l, femb_r, empty_attr, concat);
  hipLaunchKernelGGL(gemm1_kernel, dim3(100, 8), dim3(256), 0, stream,
                     concat, W1, Hpart);
  hipLaunchKernelGGL(epilogue_kernel, dim3(256), dim3(256), 0, stream,
                     Hpart, b1, W2, b2, out);
}